// Round 3
// baseline (245.274 us; speedup 1.0000x reference)
//
#include <hip/hip_runtime.h>
#include <math.h>

// Problem constants (match reference)
#define B_    8192
#define F_    64
#define V_    1000
#define E_    64
#define T_    2
#define NTOK_ 16
#define G_    4
#define D_    256
#define K_    128   // T*E
#define LN_EPS 1e-5f

#define XSP   136   // xs row stride in bf16 (128 + 8 pad: keeps 16B frag alignment, 2-way-max banks)

typedef __attribute__((ext_vector_type(8))) short  frag_ab;  // 8 bf16 = 4 VGPRs
typedef __attribute__((ext_vector_type(4))) float  frag_cd;  // 4 fp32 acc

static __device__ __forceinline__ unsigned short f2bf(float f) {
    unsigned int u = __float_as_uint(f);
    u += 0x7FFFu + ((u >> 16) & 1u);
    return (unsigned short)(u >> 16);
}

// ---- prologue: W fp32 (D,K) -> bf16 in workspace (row-major) ----
__global__ __launch_bounds__(256) void convert_w_kernel(const float* __restrict__ W,
                                                        unsigned int* __restrict__ Wb_packed) {
    const int i = blockIdx.x * 256 + threadIdx.x;   // one uint = 2 bf16
    if (i < (D_ * K_) / 2) {
        const float2 v = *(const float2*)(W + (size_t)i * 2);
        Wb_packed[i] = (unsigned int)f2bf(v.x) | ((unsigned int)f2bf(v.y) << 16);
    }
}

// One block per batch row. 256 threads = 4 waves, 8 blocks/CU (wave-capped).
// Phase 1: float4 gather + mean-pool -> xs[16][128] bf16 in LDS (only big LDS use)
// Phase 2: MFMA 16x16x32 bf16; h stays in REGISTERS (D-layout), LN stats via
//          16-lane butterfly + 512B cross-wave partial buffer; store direct.
__global__ __launch_bounds__(256, 8) void fused_tokenizer_kernel(
    const int*   __restrict__ int_feats,     // (B, F)
    const int*   __restrict__ missing_mask,  // (B, F)
    const int*   __restrict__ group_idx,     // (NTOK, G)
    const float* __restrict__ emb_tables,    // (T, F, V, E)
    const float* __restrict__ missing_emb,   // (T, F, E)
    const unsigned short* __restrict__ Wb,   // (D, K) bf16
    const float* __restrict__ bias,          // (D,)
    const float* __restrict__ gamma,         // (D,)
    const float* __restrict__ beta,          // (D,)
    float*       __restrict__ out)           // (B, NTOK, D)
{
    __shared__ unsigned short xs[NTOK_][XSP];   // 4352 B
    __shared__ unsigned int   soff[F_];         // precomputed (f*V+id)*E element offset (t=0)
    __shared__ int            smask[F_];
    __shared__ int            sg[F_];
    __shared__ float          part_s [4][NTOK_]; // per-wave LN partial sums
    __shared__ float          part_ss[4][NTOK_];

    const int tid  = threadIdx.x;
    const int b    = blockIdx.x;
    const int lane = tid & 63;
    const int wave = tid >> 6;
    const int mA   = lane & 15;
    const int q    = lane >> 4;

    if (tid < F_) {
        const int f  = tid;
        const int id = int_feats[b * F_ + f];
        soff[f]  = (unsigned int)((f * V_ + id) * E_);
        smask[f] = missing_mask[b * F_ + f];
        sg[f]    = group_idx[f];   // NTOK*G == F == 64
    }
    __syncthreads();

    // ---- Phase 1: gather + mean-pool (float4), 8 independent table loads/thread ----
#pragma unroll
    for (int i = 0; i < 2; ++i) {
        const int c  = i * 256 + tid;
        const int n  = c >> 5;
        const int r4 = c & 31;
        const int t  = r4 >> 4;
        const int e  = (r4 & 15) * 4;
        const float* bt = emb_tables + (size_t)t * (F_ * V_ * E_) + e;
        const float* mt = missing_emb + t * (F_ * E_) + e;
        float ax = 0.f, ay = 0.f, az = 0.f, aw = 0.f;
#pragma unroll
        for (int g = 0; g < G_; ++g) {
            const int f = sg[n * G_ + g];
            const float4 v = *(const float4*)(bt + soff[f]);
            float vx = v.x, vy = v.y, vz = v.z, vw = v.w;
            if (smask[f]) {
                const float4 mv = *(const float4*)(mt + f * E_);
                vx += mv.x; vy += mv.y; vz += mv.z; vw += mv.w;
            }
            ax += vx; ay += vy; az += vz; aw += vw;
        }
        unsigned int p0 = (unsigned int)f2bf(0.25f * ax) | ((unsigned int)f2bf(0.25f * ay) << 16);
        unsigned int p1 = (unsigned int)f2bf(0.25f * az) | ((unsigned int)f2bf(0.25f * aw) << 16);
        *(uint2*)(&xs[n][r4 * 4]) = make_uint2(p0, p1);
    }
    __syncthreads();

    // ---- Phase 2: MFMA + SiLU, h kept in registers ----
    frag_ab a[4];
#pragma unroll
    for (int s = 0; s < 4; ++s)
        a[s] = *(const frag_ab*)(&xs[mA][32 * s + 8 * q]);

    float hv[4][4];                 // hv[t][reg] = h[tok=q*4+reg][col=wave*64+t*16+mA]
    float ps[4]  = {0.f, 0.f, 0.f, 0.f};
    float pss[4] = {0.f, 0.f, 0.f, 0.f};

#pragma unroll
    for (int t = 0; t < 4; ++t) {
        const int nrow = wave * 64 + t * 16 + mA;
        const unsigned short* wp = Wb + (size_t)nrow * K_ + 8 * q;
        frag_cd acc = {0.f, 0.f, 0.f, 0.f};
#pragma unroll
        for (int s = 0; s < 4; ++s) {
            const frag_ab bfr = *(const frag_ab*)(wp + 32 * s);
            acc = __builtin_amdgcn_mfma_f32_16x16x32_bf16(a[s], bfr, acc, 0, 0, 0);
        }
        const float bn = bias[nrow];
#pragma unroll
        for (int reg = 0; reg < 4; ++reg) {
            const float z = acc[reg] + bn;
            const float h = z / (1.f + __expf(-z));   // silu
            hv[t][reg] = h;
            ps[reg]  += h;
            pss[reg] += h * h;
        }
    }

    // 16-lane butterfly over mA: group sum over this wave's 64 cols per token
#pragma unroll
    for (int off = 1; off < 16; off <<= 1) {
#pragma unroll
        for (int reg = 0; reg < 4; ++reg) {
            ps[reg]  += __shfl_xor(ps[reg],  off, 64);
            pss[reg] += __shfl_xor(pss[reg], off, 64);
        }
    }
    if (mA == 0) {
        *(float4*)(&part_s [wave][q * 4]) = make_float4(ps[0],  ps[1],  ps[2],  ps[3]);
        *(float4*)(&part_ss[wave][q * 4]) = make_float4(pss[0], pss[1], pss[2], pss[3]);
    }
    __syncthreads();

    // cross-wave totals for this lane's 4 tokens (q*4 .. q*4+3)
    float4 S0 = *(const float4*)(&part_s [0][q * 4]);
    float4 S1 = *(const float4*)(&part_s [1][q * 4]);
    float4 S2 = *(const float4*)(&part_s [2][q * 4]);
    float4 S3 = *(const float4*)(&part_s [3][q * 4]);
    float4 T0 = *(const float4*)(&part_ss[0][q * 4]);
    float4 T1 = *(const float4*)(&part_ss[1][q * 4]);
    float4 T2 = *(const float4*)(&part_ss[2][q * 4]);
    float4 T3 = *(const float4*)(&part_ss[3][q * 4]);

    float mu[4], rs[4];
    {
        const float s[4]  = {S0.x + S1.x + S2.x + S3.x, S0.y + S1.y + S2.y + S3.y,
                             S0.z + S1.z + S2.z + S3.z, S0.w + S1.w + S2.w + S3.w};
        const float ss[4] = {T0.x + T1.x + T2.x + T3.x, T0.y + T1.y + T2.y + T3.y,
                             T0.z + T1.z + T2.z + T3.z, T0.w + T1.w + T2.w + T3.w};
#pragma unroll
        for (int reg = 0; reg < 4; ++reg) {
            mu[reg] = s[reg] * (1.f / D_);
            const float var = ss[reg] * (1.f / D_) - mu[reg] * mu[reg];
            rs[reg] = rsqrtf(var + LN_EPS);
        }
    }

    // ---- store directly from registers: per (t,reg) a 4x64B-segment store ----
    const size_t obase = (size_t)b * (NTOK_ * D_);
#pragma unroll
    for (int t = 0; t < 4; ++t) {
        const int col = wave * 64 + t * 16 + mA;
        const float gm = gamma[col];
        const float bb = beta[col];
        float* op = out + obase + col;
#pragma unroll
        for (int reg = 0; reg < 4; ++reg) {
            const int tok = q * 4 + reg;
            op[(size_t)tok * D_] = (hv[t][reg] - mu[reg]) * rs[reg] * gm + bb;
        }
    }
}

extern "C" void kernel_launch(void* const* d_in, const int* in_sizes, int n_in,
                              void* d_out, int out_size, void* d_ws, size_t ws_size,
                              hipStream_t stream) {
    const int*   int_feats    = (const int*)  d_in[0];
    const int*   missing_mask = (const int*)  d_in[1];
    const int*   group_idx    = (const int*)  d_in[2];
    const float* emb_tables   = (const float*)d_in[3];
    const float* missing_emb  = (const float*)d_in[4];
    const float* W            = (const float*)d_in[5];
    const float* bias         = (const float*)d_in[6];
    const float* gamma        = (const float*)d_in[7];
    const float* beta         = (const float*)d_in[8];
    float* out = (float*)d_out;

    unsigned short* Wb = (unsigned short*)d_ws;   // 64 KB bf16 copy of W

    convert_w_kernel<<<(D_ * K_ / 2 + 255) / 256, 256, 0, stream>>>(W, (unsigned int*)Wb);
    fused_tokenizer_kernel<<<B_, 256, 0, stream>>>(
        int_feats, missing_mask, group_idx, emb_tables, missing_emb,
        Wb, bias, gamma, beta, out);
}